// Round 3
// baseline (599.455 us; speedup 1.0000x reference)
//
#include <hip/hip_runtime.h>
#include <stdint.h>
#include <stddef.h>

// Problem constants
#define TOK   4096   // B*S
#define DDIM  1024
#define EXP   8
#define HDIM  4096

typedef __bf16 bf16x8 __attribute__((ext_vector_type(8)));
typedef __bf16 bf16x4 __attribute__((ext_vector_type(4)));
typedef __bf16 bf16x2 __attribute__((ext_vector_type(2)));
typedef float  f32x4  __attribute__((ext_vector_type(4)));

// Workspace layout (all offsets 256-aligned). Total ~202 MB.
#define OFF_COUNTS 0ull
#define OFF_PREFIX 256ull
#define OFF_PERM   512ull                         // 8*4096*4  = 131072
#define OFF_WGT    (OFF_PERM + 131072ull)         // 8*4096*4  = 131072
#define OFF_XBF    (OFF_WGT + 131072ull)          // 4096*1024*2 = 8388608
#define OFF_W1T    (OFF_XBF + 8388608ull)         // 8*4096*1024*2 = 67108864
#define OFF_W2T    (OFF_W1T + 67108864ull)        // 8*1024*4096*2 = 67108864
#define OFF_HBF    (OFF_W2T + 67108864ull)        // (8192+128)*4096*2 = 68157440
#define OFF_T2E    (OFF_HBF + 68157440ull)        // 4096*16 = 65536
// Y (split-K=4 bf16 partials, 4*8192*1024*2 = 67108864 B) ALIASES OFF_W1T exactly:
// W1t is dead after gemm1; gemm2 writes Y there, combine reads it.

__device__ __forceinline__ void load16_lds(const void* g, void* l) {
  // width=16 direct global->LDS DMA; LDS dest must be wave-uniform base + lane*16
  __builtin_amdgcn_global_load_lds((__attribute__((address_space(1))) void*)g,
                                   (__attribute__((address_space(3))) void*)l,
                                   16, 0, 0);
}

// 64x64 fp32->bf16 transpose tile body, shared by prep (W1) and gemm1 (W2 role).
// tileT[n][k] bf16 with 16B-chunk XOR swizzle: byte = n*128 + ((k*2) ^ (((n>>2)&7)<<4)).
__device__ __forceinline__ void transpose_tile64(const float* __restrict__ src,
                                                 __bf16* __restrict__ dst,
                                                 int Nd, int Kd, char* tb8, int tid)
{
  const int lr2 = (tid >> 4) * 2;      // even row (=k) base 0..30
  const int lc  = (tid & 15) * 4;      // n base
#pragma unroll
  for (int p = 0; p < 2; ++p) {
    const int r = p * 32 + lr2;
    float4 va = *(const float4*)(src + (size_t)r * Nd + lc);
    float4 vb = *(const float4*)(src + (size_t)(r + 1) * Nd + lc);
    float a4[4] = { va.x, va.y, va.z, va.w };
    float b4[4] = { vb.x, vb.y, vb.z, vb.w };
#pragma unroll
    for (int j = 0; j < 4; ++j) {
      const int n = lc + j;
      bf16x2 w = { (__bf16)a4[j], (__bf16)b4[j] };   // k=r, k=r+1
      *(bf16x2*)(tb8 + n * 128 + ((r * 2) ^ (((n >> 2) & 7) << 4))) = w;
    }
  }
  __syncthreads();
  const int n2 = tid >> 2, cb = tid & 3;
  const int sw = (n2 >> 2) & 7;
#pragma unroll
  for (int h = 0; h < 2; ++h) {
    const int c = cb + h * 4;                        // 16B chunk index (8 k's)
    bf16x8 o = *(const bf16x8*)(tb8 + n2 * 128 + ((c ^ sw) << 4));
    *(bf16x8*)(dst + (size_t)n2 * Kd + c * 8) = o;
  }
}

// ---------------- prep: gate (blocks 0..63) + W1 transpose (blocks 64..8255) -------------
// Round-7: W2 transpose moved INTO gemm1's dispatch (interleaved on odd bids) — gemm1 runs
// at 16% HBM / 24% MfmaUtil, so the transpose's pure-BW work hides in its stall slots.
__global__ __launch_bounds__(256) void prep_kernel(
    const float* __restrict__ W1, __bf16* __restrict__ W1t,
    const float* __restrict__ x, const float* __restrict__ Wg,
    __bf16* __restrict__ x_bf, int* __restrict__ counts,
    int* __restrict__ perm, float* __restrict__ wgt,
    int4* __restrict__ tok2exp)
{
  __shared__ __align__(16) float tile[2112];   // 8448 B
  const int bid = blockIdx.x;
  const int tid = threadIdx.x;

  if (bid < 64) {
    // ---- gate role: fp32 logits, top-2, softmax (folds mean/8), routing lists, x->bf16 ----
    const int lane = tid & 63;
    const int wid  = tid >> 6;

    int*   lcnt   = (int*)tile;          // [8]  block-local expert counts
    int*   gbase  = lcnt + 8;            // [8]  global base positions
    int*   rec_e  = gbase + 8;           // [64] e0 | e1<<8
    int*   rec_p  = rec_e + 64;          // [64] lp0 | lp1<<16
    float* rec_w0 = (float*)(rec_p + 64);// [64]
    float* rec_w1 = rec_w0 + 64;         // [64]

    if (tid < 8) lcnt[tid] = 0;
    __syncthreads();

#pragma unroll 1
    for (int i = 0; i < 16; ++i) {
      const int li = wid * 16 + i;
      const int t  = bid * 64 + li;
      const float* xr = x + (size_t)t * DDIM;

      float acc[EXP];
#pragma unroll
      for (int e = 0; e < EXP; ++e) acc[e] = 0.f;

#pragma unroll
      for (int it = 0; it < 4; ++it) {
        const int d0 = it * 256 + lane * 4;
        float4 xv = *(const float4*)(xr + d0);
        bf16x4 xb = { (__bf16)xv.x, (__bf16)xv.y, (__bf16)xv.z, (__bf16)xv.w };
        *(bf16x4*)(x_bf + (size_t)t * DDIM + d0) = xb;
        const float* wrow = Wg + (size_t)d0 * EXP;
        float xs[4] = { xv.x, xv.y, xv.z, xv.w };
#pragma unroll
        for (int u = 0; u < 4; ++u) {
          float4 wa = *(const float4*)(wrow + u * 8);
          float4 wb = *(const float4*)(wrow + u * 8 + 4);
          acc[0] += xs[u] * wa.x; acc[1] += xs[u] * wa.y;
          acc[2] += xs[u] * wa.z; acc[3] += xs[u] * wa.w;
          acc[4] += xs[u] * wb.x; acc[5] += xs[u] * wb.y;
          acc[6] += xs[u] * wb.z; acc[7] += xs[u] * wb.w;
        }
      }
#pragma unroll
      for (int e = 0; e < EXP; ++e) {
        float v = acc[e];
#pragma unroll
        for (int s = 32; s > 0; s >>= 1) v += __shfl_down(v, s, 64);
        acc[e] = v;
      }
      if (lane == 0) {
        int e0 = 0; float g0 = acc[0];
#pragma unroll
        for (int e = 1; e < EXP; ++e) if (acc[e] > g0) { g0 = acc[e]; e0 = e; }
        int e1 = 0; float g1 = -3.4e38f;
#pragma unroll
        for (int e = 0; e < EXP; ++e) if (e != e0 && acc[e] > g1) { g1 = acc[e]; e1 = e; }
        float ex = __expf(g1 - g0);
        float m0 = 1.f / (1.f + ex);
        float m1 = ex  / (1.f + ex);
        int lp0 = atomicAdd(&lcnt[e0], 1);
        int lp1 = atomicAdd(&lcnt[e1], 1);
        rec_e[li]  = e0 | (e1 << 8);
        rec_p[li]  = lp0 | (lp1 << 16);
        rec_w0[li] = m0 * 0.125f;
        rec_w1[li] = m1 * 0.125f;
      }
    }
    __syncthreads();
    if (tid < 8) gbase[tid] = atomicAdd(&counts[tid], lcnt[tid]);
    __syncthreads();
    if (tid < 64) {
      const int t = bid * 64 + tid;
      const int ee = rec_e[tid], pp = rec_p[tid];
      const int e0 = ee & 0xff, e1 = ee >> 8;
      const int p0 = gbase[e0] + (pp & 0xffff);
      const int p1 = gbase[e1] + (pp >> 16);
      perm[e0 * TOK + p0] = t;  wgt[e0 * TOK + p0] = rec_w0[tid];
      perm[e1 * TOK + p1] = t;  wgt[e1 * TOK + p1] = rec_w1[tid];
      tok2exp[t] = make_int4(e0, p0, e1, p1);
    }
    return;
  }

  // ---- W1 transpose: fp32 [E][1024][4096] -> bf16 [E][4096][1024], 64x64 tile ----
  const int tb  = bid - 64;
  const int e   = tb >> 10;
  const int t10 = tb & 1023;
  const int tk = t10 & 15, tn = t10 >> 4;
  const float* src = W1 + ((size_t)e * 1024 + tk * 64) * 4096 + tn * 64;
  __bf16*      dst = W1t + ((size_t)e * 4096 + tn * 64) * 1024 + tk * 64;
  transpose_tile64(src, dst, 4096, 1024, (char*)tile, tid);
}

// ---------------- grouped GEMM1 (even bids) + W2 transpose (odd bids) --------------------
// Round-7: counted-vmcnt depth-2 pipeline (T4): 3 LDS buffer pairs, raw s_barrier (no
// implicit vmcnt(0) drain — __syncthreads would emit one), asm vmcnt(4) per iter so the
// loads for buf i+1, i+2 stay in flight across two full compute phases. Stages are issued
// unconditionally (last two are dummies into a never-read buffer; 64B over-read lands in
// adjacent mapped workspace) to keep the vmcnt ledger uniform at 8 outstanding.
__global__ __launch_bounds__(256, 2) void gemm1_kernel(
    const __bf16* __restrict__ x_bf, const __bf16* __restrict__ W1t,
    const float* __restrict__ b1, __bf16* __restrict__ h_bf,
    const int* __restrict__ perm, const int* __restrict__ counts,
    const float* __restrict__ W2, __bf16* __restrict__ W2t)
{
  __shared__ __align__(16) __bf16 As[3][4096];
  __shared__ __align__(16) __bf16 Bs[3][4096];
  const int bid = blockIdx.x;
  const int tid = threadIdx.x;

  if (bid & 1) {
    // ---- W2 transpose role: fp32 [E][4096][1024] -> bf16 [E][1024][4096], 64x64 tile ----
    const int p   = bid >> 1;
    const int e   = p >> 10;
    const int t10 = p & 1023;
    const int tk = t10 >> 4, tn = t10 & 15;
    const float* src = W2 + ((size_t)e * 4096 + tk * 64) * 1024 + tn * 64;
    __bf16*      dst = W2t + ((size_t)e * 1024 + tn * 64) * 4096 + tk * 64;
    transpose_tile64(src, dst, 1024, 4096, (char*)As, tid);
    return;
  }

  const int g   = bid >> 1;
  const int e   = g >> 10;
  const int mt  = (g >> 5) & 31;
  const int nt  = g & 31;
  const int cnt = counts[e];
  if (mt * 128 >= cnt) return;
  int pfx = 0;
#pragma unroll
  for (int i = 0; i < EXP; ++i) if (i < e) pfx += counts[i];

  const int lane = tid & 63, wid = tid >> 6;
  const int wm = wid & 1, wn = wid >> 1;
  const int qd = lane >> 4, l15 = lane & 15;

  const int rA0 = tid >> 2, rA1 = rA0 + 64;
  const int pA0 = (tid & 3) ^ ((rA0 >> 1) & 3);
  const int pA1 = (tid & 3) ^ ((rA1 >> 1) & 3);
  int mA0 = mt * 128 + rA0; if (mA0 >= cnt) mA0 = cnt - 1;
  int mA1 = mt * 128 + rA1; if (mA1 >= cnt) mA1 = cnt - 1;
  const int tok0 = perm[e * TOK + mA0];
  const int tok1 = perm[e * TOK + mA1];
  const __bf16* gA0 = x_bf + (size_t)tok0 * DDIM + pA0 * 8;
  const __bf16* gA1 = x_bf + (size_t)tok1 * DDIM + pA1 * 8;
  const __bf16* Wte = W1t + (size_t)e * HDIM * DDIM;
  const __bf16* gB0 = Wte + (size_t)(nt * 128 + rA0) * DDIM + pA0 * 8;
  const __bf16* gB1 = Wte + (size_t)(nt * 128 + rA1) * DDIM + pA1 * 8;

#define STAGE1(buf, kk) do { \
    load16_lds(gA0 + (kk), &As[buf][tid * 8]); \
    load16_lds(gA1 + (kk), &As[buf][(tid + 256) * 8]); \
    load16_lds(gB0 + (kk), &Bs[buf][tid * 8]); \
    load16_lds(gB1 + (kk), &Bs[buf][(tid + 256) * 8]); \
  } while (0)

  f32x4 acc[4][4] = {};

  STAGE1(0, 0);
  STAGE1(1, 32);
  int cur = 0;
#pragma unroll 1
  for (int it = 0; it < 32; ++it) {
    asm volatile("s_waitcnt vmcnt(4)" ::: "memory");
    __builtin_amdgcn_s_barrier();
    __builtin_amdgcn_sched_barrier(0);
    int nb = cur + 2; if (nb >= 3) nb -= 3;
    STAGE1(nb, (it + 2) * 32);          // dummy for it>=30: never read, in-bounds over-read
    bf16x8 af[4], bfr[4];
#pragma unroll
    for (int i = 0; i < 4; ++i) {
      int r = wm * 64 + i * 16 + l15;
      int ch = r * 4 + (qd ^ ((r >> 1) & 3));
      af[i] = *(const bf16x8*)(&As[cur][ch * 8]);
    }
#pragma unroll
    for (int j = 0; j < 4; ++j) {
      int r = wn * 64 + j * 16 + l15;
      int ch = r * 4 + (qd ^ ((r >> 1) & 3));
      bfr[j] = *(const bf16x8*)(&Bs[cur][ch * 8]);
    }
#pragma unroll
    for (int i = 0; i < 4; ++i)
#pragma unroll
      for (int j = 0; j < 4; ++j)
        acc[i][j] = __builtin_amdgcn_mfma_f32_16x16x32_bf16(af[i], bfr[j], acc[i][j], 0, 0, 0);
    cur += 1; if (cur == 3) cur = 0;
  }
#undef STAGE1

  const float* b1e = b1 + (size_t)e * HDIM;
#pragma unroll
  for (int i = 0; i < 4; ++i) {
#pragma unroll
    for (int v = 0; v < 4; ++v) {
      const int rl = wm * 64 + i * 16 + qd * 4 + v;
      const int m  = mt * 128 + rl;
      if (m < cnt) {
        __bf16* hrow = h_bf + (size_t)(pfx + m) * HDIM;
#pragma unroll
        for (int j = 0; j < 4; ++j) {
          const int col = nt * 128 + wn * 64 + j * 16 + l15;
          float hv = acc[i][j][v] + b1e[col];
          hv = fmaxf(hv, 0.f);
          hrow[col] = (__bf16)hv;
        }
      }
    }
  }
}

// ---------------- grouped GEMM2 (split-K=4, bf16 partials, counted-vmcnt pipeline) -------
__global__ __launch_bounds__(256, 2) void gemm2_kernel(
    const __bf16* __restrict__ h_bf, const __bf16* __restrict__ W2t,
    __bf16* __restrict__ Y,
    const int* __restrict__ counts)
{
  const int bid = blockIdx.x;
  const int ks  = bid & 3;
  const int nt  = (bid >> 2) & 7;
  const int mt  = (bid >> 5) & 31;
  const int e   = bid >> 10;
  const int cnt = counts[e];
  if (mt * 128 >= cnt) return;
  int pfx = 0;
#pragma unroll
  for (int i = 0; i < EXP; ++i) if (i < e) pfx += counts[i];

  __shared__ __align__(16) __bf16 As[3][4096];
  __shared__ __align__(16) __bf16 Bs[3][4096];

  const int tid  = threadIdx.x;
  const int lane = tid & 63, wid = tid >> 6;
  const int wm = wid & 1, wn = wid >> 1;
  const int qd = lane >> 4, l15 = lane & 15;

  const int rA0 = tid >> 2, rA1 = rA0 + 64;
  const int pA0 = (tid & 3) ^ ((rA0 >> 1) & 3);
  const int pA1 = (tid & 3) ^ ((rA1 >> 1) & 3);
  const __bf16* gA0 = h_bf + (size_t)(pfx + mt * 128 + rA0) * HDIM + pA0 * 8;
  const __bf16* gA1 = h_bf + (size_t)(pfx + mt * 128 + rA1) * HDIM + pA1 * 8;
  const __bf16* Wte = W2t + (size_t)e * DDIM * HDIM;
  const __bf16* gB0 = Wte + (size_t)(nt * 128 + rA0) * HDIM + pA0 * 8;
  const __bf16* gB1 = Wte + (size_t)(nt * 128 + rA1) * HDIM + pA1 * 8;

#define STAGE2(buf, kk) do { \
    load16_lds(gA0 + (kk), &As[buf][tid * 8]); \
    load16_lds(gA1 + (kk), &As[buf][(tid + 256) * 8]); \
    load16_lds(gB0 + (kk), &Bs[buf][tid * 8]); \
    load16_lds(gB1 + (kk), &Bs[buf][(tid + 256) * 8]); \
  } while (0)

  f32x4 acc[4][4] = {};

  const int kbeg = ks * (HDIM / 4);
  STAGE2(0, kbeg);
  STAGE2(1, kbeg + 32);
  int cur = 0;
#pragma unroll 1
  for (int it = 0; it < 32; ++it) {
    asm volatile("s_waitcnt vmcnt(4)" ::: "memory");
    __builtin_amdgcn_s_barrier();
    __builtin_amdgcn_sched_barrier(0);
    int nb = cur + 2; if (nb >= 3) nb -= 3;
    STAGE2(nb, kbeg + (it + 2) * 32);   // dummy for it>=30: never read, in-bounds over-read
    bf16x8 af[4], bfr[4];
#pragma unroll
    for (int i = 0; i < 4; ++i) {
      int r = wm * 64 + i * 16 + l15;
      int ch = r * 4 + (qd ^ ((r >> 1) & 3));
      af[i] = *(const bf16x8*)(&As[cur][ch * 8]);
    }
#pragma unroll
    for (int j = 0; j < 4; ++j) {
      int r = wn * 64 + j * 16 + l15;
      int ch = r * 4 + (qd ^ ((r >> 1) & 3));
      bfr[j] = *(const bf16x8*)(&Bs[cur][ch * 8]);
    }
#pragma unroll
    for (int i = 0; i < 4; ++i)
#pragma unroll
      for (int j = 0; j < 4; ++j)
        acc[i][j] = __builtin_amdgcn_mfma_f32_16x16x32_bf16(af[i], bfr[j], acc[i][j], 0, 0, 0);
    cur += 1; if (cur == 3) cur = 0;
  }
#undef STAGE2

  __bf16* Ys = Y + (size_t)ks * (2 * TOK) * DDIM;
#pragma unroll
  for (int i = 0; i < 4; ++i) {
#pragma unroll
    for (int v = 0; v < 4; ++v) {
      const int rl = wm * 64 + i * 16 + qd * 4 + v;
      const int m  = mt * 128 + rl;
      if (m < cnt) {
        __bf16* yrow = Ys + (size_t)(pfx + m) * DDIM;
#pragma unroll
        for (int j = 0; j < 4; ++j) {
          const int col = nt * 128 + wn * 64 + j * 16 + l15;
          yrow[col] = (__bf16)acc[i][j][v];
        }
      }
    }
  }
}

// ---------------- combine: out[t] = sum_j w_j * (sum_s Y[s][g_j] + b2[e_j]) ----------------
__global__ __launch_bounds__(256) void combine_kernel(
    const __bf16* __restrict__ Y, const float* __restrict__ b2,
    const float* __restrict__ wgt, const int4* __restrict__ tok2exp,
    const int* __restrict__ counts, float* __restrict__ out)
{
  const int t = blockIdx.x;
  const int c = threadIdx.x * 4;
  const int4 m = tok2exp[t];
  int base0 = 0, base1 = 0;
#pragma unroll
  for (int i = 0; i < EXP; ++i) {
    int cc = counts[i];
    if (i < m.x) base0 += cc;
    if (i < m.z) base1 += cc;
  }
  const int g0 = base0 + m.y;
  const int g1 = base1 + m.w;
  const float w0 = wgt[m.x * TOK + m.y];
  const float w1 = wgt[m.z * TOK + m.w];
  const size_t slab = (size_t)(2 * TOK) * DDIM;

  float s0x = 0.f, s0y = 0.f, s0z = 0.f, s0w = 0.f;
  float s1x = 0.f, s1y = 0.f, s1z = 0.f, s1w = 0.f;
#pragma unroll
  for (int s = 0; s < 4; ++s) {
    bf16x4 a = *(const bf16x4*)(Y + s * slab + (size_t)g0 * DDIM + c);
    bf16x4 b = *(const bf16x4*)(Y + s * slab + (size_t)g1 * DDIM + c);
    s0x += (float)a[0]; s0y += (float)a[1]; s0z += (float)a[2]; s0w += (float)a[3];
    s1x += (float)b[0]; s1y += (float)b[1]; s1z += (float)b[2]; s1w += (float)b[3];
  }
  float4 be0 = *(const float4*)(b2 + (size_t)m.x * DDIM + c);
  float4 be1 = *(const float4*)(b2 + (size_t)m.z * DDIM + c);
  float4 r;
  r.x = w0 * (s0x + be0.x) + w1 * (s1x + be1.x);
  r.y = w0 * (s0y + be0.y) + w1 * (s1y + be1.y);
  r.z = w0 * (s0z + be0.z) + w1 * (s1z + be1.z);
  r.w = w0 * (s0w + be0.w) + w1 * (s1w + be1.w);
  *(float4*)(out + (size_t)t * DDIM + c) = r;
}

extern "C" void kernel_launch(void* const* d_in, const int* in_sizes, int n_in,
                              void* d_out, int out_size, void* d_ws, size_t ws_size,
                              hipStream_t stream)
{
  const float* x  = (const float*)d_in[0];
  const float* Wg = (const float*)d_in[1];
  const float* W1 = (const float*)d_in[2];
  const float* b1 = (const float*)d_in[3];
  const float* W2 = (const float*)d_in[4];
  const float* b2 = (const float*)d_in[5];
  float* out = (float*)d_out;

  char* ws = (char*)d_ws;
  int*    counts  = (int*)(ws + OFF_COUNTS);
  int*    perm    = (int*)(ws + OFF_PERM);
  float*  wgt     = (float*)(ws + OFF_WGT);
  __bf16* x_bf    = (__bf16*)(ws + OFF_XBF);
  __bf16* W1t     = (__bf16*)(ws + OFF_W1T);
  __bf16* W2t     = (__bf16*)(ws + OFF_W2T);
  __bf16* h_bf    = (__bf16*)(ws + OFF_HBF);
  int4*   tok2exp = (int4*)(ws + OFF_T2E);
  __bf16* Y       = (__bf16*)(ws + OFF_W1T);   // aliases W1t (dead after gemm1)

  hipMemsetAsync(counts, 0, 256, stream);

  // prep: 64 gate blocks first, then 8192 W1-transpose blocks
  prep_kernel<<<64 + 8192, 256, 0, stream>>>(W1, W1t, x, Wg, x_bf, counts, perm, wgt, tok2exp);
  // gemm1 (even bids) interleaved with W2 transpose (odd bids)
  gemm1_kernel<<<2 * EXP * 32 * 32, 256, 0, stream>>>(x_bf, W1t, b1, h_bf, perm, counts, W2, W2t);
  gemm2_kernel<<<EXP * 32 * 8 * 4, 256, 0, stream>>>(h_bf, W2t, Y, counts);
  combine_kernel<<<TOK, 256, 0, stream>>>(Y, b2, wgt, tok2exp, counts, out);
}

// Round 4
// 520.928 us; speedup vs baseline: 1.1507x; 1.1507x over previous
//
#include <hip/hip_runtime.h>
#include <stdint.h>
#include <stddef.h>

// Problem constants
#define TOK   4096   // B*S
#define DDIM  1024
#define EXP   8
#define HDIM  4096

typedef __bf16 bf16x8 __attribute__((ext_vector_type(8)));
typedef __bf16 bf16x4 __attribute__((ext_vector_type(4)));
typedef __bf16 bf16x2 __attribute__((ext_vector_type(2)));
typedef float  f32x4  __attribute__((ext_vector_type(4)));

// Workspace layout (all offsets 256-aligned). Total ~202 MB.
#define OFF_COUNTS 0ull
#define OFF_PREFIX 256ull
#define OFF_PERM   512ull                         // 8*4096*4  = 131072
#define OFF_WGT    (OFF_PERM + 131072ull)         // 8*4096*4  = 131072
#define OFF_XBF    (OFF_WGT + 131072ull)          // 4096*1024*2 = 8388608
#define OFF_W1T    (OFF_XBF + 8388608ull)         // 8*4096*1024*2 = 67108864
#define OFF_W2T    (OFF_W1T + 67108864ull)        // 8*1024*4096*2 = 67108864
#define OFF_HBF    (OFF_W2T + 67108864ull)        // (8192+128)*4096*2 = 68157440
#define OFF_T2E    (OFF_HBF + 68157440ull)        // 4096*16 = 65536
// Y (split-K=4 bf16 partials, 4*8192*1024*2 = 67108864 B) ALIASES OFF_W1T exactly:
// W1t is dead after gemm1; gemm2 writes Y there, combine reads it.

__device__ __forceinline__ void load16_lds(const void* g, void* l) {
  // width=16 direct global->LDS DMA; LDS dest must be wave-uniform base + lane*16
  __builtin_amdgcn_global_load_lds((__attribute__((address_space(1))) void*)g,
                                   (__attribute__((address_space(3))) void*)l,
                                   16, 0, 0);
}

// ---------------- merged prep ----------------------------------------------------------
// Blocks 0..63: gating (64 tokens/block, LDS-aggregated routing -> 8 global atomics/block).
// Blocks 64..16447: transpose fp32 [E][K][N] -> bf16 [E][N][K] for W1, W2.
// Round-8: reverted to round-2 shape — round-3's gemm1-interleaved W2 transpose collapsed
// occupancy (19%) and broke the gemm L2 block order (218 us combined). Separate prep with
// the bf16-before-LDS tile (8.4 KB) is the known-good form.
__global__ __launch_bounds__(256) void prep_kernel(
    const float* __restrict__ W1, const float* __restrict__ W2,
    __bf16* __restrict__ W1t, __bf16* __restrict__ W2t,
    const float* __restrict__ x, const float* __restrict__ Wg,
    __bf16* __restrict__ x_bf, int* __restrict__ counts,
    int* __restrict__ perm, float* __restrict__ wgt,
    int4* __restrict__ tok2exp)
{
  __shared__ __align__(16) float tile[2112];   // 8448 B
  const int bid = blockIdx.x;
  const int tid = threadIdx.x;

  if (bid < 64) {
    // ---- gate role: fp32 logits, top-2, softmax (folds mean/8), routing lists, x->bf16 ----
    const int lane = tid & 63;
    const int wid  = tid >> 6;

    int*   lcnt   = (int*)tile;          // [8]  block-local expert counts
    int*   gbase  = lcnt + 8;            // [8]  global base positions
    int*   rec_e  = gbase + 8;           // [64] e0 | e1<<8
    int*   rec_p  = rec_e + 64;          // [64] lp0 | lp1<<16
    float* rec_w0 = (float*)(rec_p + 64);// [64]
    float* rec_w1 = rec_w0 + 64;         // [64]

    if (tid < 8) lcnt[tid] = 0;
    __syncthreads();

#pragma unroll 1
    for (int i = 0; i < 16; ++i) {
      const int li = wid * 16 + i;
      const int t  = bid * 64 + li;
      const float* xr = x + (size_t)t * DDIM;

      float acc[EXP];
#pragma unroll
      for (int e = 0; e < EXP; ++e) acc[e] = 0.f;

#pragma unroll
      for (int it = 0; it < 4; ++it) {
        const int d0 = it * 256 + lane * 4;
        float4 xv = *(const float4*)(xr + d0);
        bf16x4 xb = { (__bf16)xv.x, (__bf16)xv.y, (__bf16)xv.z, (__bf16)xv.w };
        *(bf16x4*)(x_bf + (size_t)t * DDIM + d0) = xb;
        const float* wrow = Wg + (size_t)d0 * EXP;
        float xs[4] = { xv.x, xv.y, xv.z, xv.w };
#pragma unroll
        for (int u = 0; u < 4; ++u) {
          float4 wa = *(const float4*)(wrow + u * 8);
          float4 wb = *(const float4*)(wrow + u * 8 + 4);
          acc[0] += xs[u] * wa.x; acc[1] += xs[u] * wa.y;
          acc[2] += xs[u] * wa.z; acc[3] += xs[u] * wa.w;
          acc[4] += xs[u] * wb.x; acc[5] += xs[u] * wb.y;
          acc[6] += xs[u] * wb.z; acc[7] += xs[u] * wb.w;
        }
      }
#pragma unroll
      for (int e = 0; e < EXP; ++e) {
        float v = acc[e];
#pragma unroll
        for (int s = 32; s > 0; s >>= 1) v += __shfl_down(v, s, 64);
        acc[e] = v;
      }
      if (lane == 0) {
        int e0 = 0; float g0 = acc[0];
#pragma unroll
        for (int e = 1; e < EXP; ++e) if (acc[e] > g0) { g0 = acc[e]; e0 = e; }
        int e1 = 0; float g1 = -3.4e38f;
#pragma unroll
        for (int e = 0; e < EXP; ++e) if (e != e0 && acc[e] > g1) { g1 = acc[e]; e1 = e; }
        float ex = __expf(g1 - g0);
        float m0 = 1.f / (1.f + ex);
        float m1 = ex  / (1.f + ex);
        int lp0 = atomicAdd(&lcnt[e0], 1);
        int lp1 = atomicAdd(&lcnt[e1], 1);
        rec_e[li]  = e0 | (e1 << 8);
        rec_p[li]  = lp0 | (lp1 << 16);
        rec_w0[li] = m0 * 0.125f;
        rec_w1[li] = m1 * 0.125f;
      }
    }
    __syncthreads();
    if (tid < 8) gbase[tid] = atomicAdd(&counts[tid], lcnt[tid]);
    __syncthreads();
    if (tid < 64) {
      const int t = bid * 64 + tid;
      const int ee = rec_e[tid], pp = rec_p[tid];
      const int e0 = ee & 0xff, e1 = ee >> 8;
      const int p0 = gbase[e0] + (pp & 0xffff);
      const int p1 = gbase[e1] + (pp >> 16);
      perm[e0 * TOK + p0] = t;  wgt[e0 * TOK + p0] = rec_w0[tid];
      perm[e1 * TOK + p1] = t;  wgt[e1 * TOK + p1] = rec_w1[tid];
      tok2exp[t] = make_int4(e0, p0, e1, p1);
    }
    return;
  }

  // ---- transpose role: fp32 [E][K][N] -> bf16 [E][N][K], 64x64 tile per block ----
  const int tb    = bid - 64;
  const int which = tb >> 13;
  const int e     = (tb >> 10) & 7;
  const int t10   = tb & 1023;
  const float* src; __bf16* dst; int Kd, Nd, tk, tn;
  if (which == 0) { Kd = 1024; Nd = 4096; src = W1; dst = W1t; tk = t10 & 15; tn = t10 >> 4; }
  else            { Kd = 4096; Nd = 1024; src = W2; dst = W2t; tk = t10 >> 4; tn = t10 & 15; }
  const int k0 = tk * 64, n0 = tn * 64;
  src += ((size_t)e * Kd + k0) * Nd + n0;
  dst += ((size_t)e * Nd + n0) * Kd + k0;

  char* tb8 = (char*)tile;   // bf16 tileT[n][k]: byte = n*128 + ((k*2) ^ (((n>>2)&7)<<4))
  const int lr2 = (tid >> 4) * 2;      // even row (=k) base 0..30
  const int lc  = (tid & 15) * 4;      // n base
#pragma unroll
  for (int p = 0; p < 2; ++p) {
    const int r = p * 32 + lr2;
    float4 va = *(const float4*)(src + (size_t)r * Nd + lc);
    float4 vb = *(const float4*)(src + (size_t)(r + 1) * Nd + lc);
    float a4[4] = { va.x, va.y, va.z, va.w };
    float b4[4] = { vb.x, vb.y, vb.z, vb.w };
#pragma unroll
    for (int j = 0; j < 4; ++j) {
      const int n = lc + j;
      bf16x2 w = { (__bf16)a4[j], (__bf16)b4[j] };   // k=r, k=r+1
      *(bf16x2*)(tb8 + n * 128 + ((r * 2) ^ (((n >> 2) & 7) << 4))) = w;
    }
  }
  __syncthreads();
  const int n2 = tid >> 2, cb = tid & 3;
  const int sw = (n2 >> 2) & 7;
#pragma unroll
  for (int h = 0; h < 2; ++h) {
    const int c = cb + h * 4;                        // 16B chunk index (8 k's)
    bf16x8 o = *(const bf16x8*)(tb8 + n2 * 128 + ((c ^ sw) << 4));
    *(bf16x8*)(dst + (size_t)n2 * Kd + c * 8) = o;
  }
}

// ---------------- grouped GEMM1: h = relu(gather(x) @ W1_e + b1_e), bf16 out ----------------
// Round-3 block order (e slow, mt middle, nt FAST): co-resident blocks share the gathered
// A-tile and stream W1t sequentially. Round-8: counted-vmcnt depth-1 pipeline, 2 LDS buffer
// pairs (32 KB only — round-3's 48 KB collapsed occupancy): STAGE(next) -> vmcnt(4) (current
// buf's loads done, next's 4 stay in flight) -> raw s_barrier (NO vmcnt(0) drain; that drain
// is what capped round-1/2 at MfmaUtil ~25%) -> ds_read+MFMA -> s_barrier (WAR). Last iter
// peeled with vmcnt(0). sched_barrier(0) fences motion across barriers.
__global__ __launch_bounds__(256, 2) void gemm1_kernel(
    const __bf16* __restrict__ x_bf, const __bf16* __restrict__ W1t,
    const float* __restrict__ b1, __bf16* __restrict__ h_bf,
    const int* __restrict__ perm, const int* __restrict__ counts)
{
  const int bid = blockIdx.x;
  const int e   = bid >> 10;
  const int mt  = (bid >> 5) & 31;
  const int nt  = bid & 31;
  const int cnt = counts[e];
  if (mt * 128 >= cnt) return;
  int pfx = 0;
#pragma unroll
  for (int i = 0; i < EXP; ++i) if (i < e) pfx += counts[i];

  __shared__ __align__(16) __bf16 As[2][4096];
  __shared__ __align__(16) __bf16 Bs[2][4096];

  const int tid  = threadIdx.x;
  const int lane = tid & 63, wid = tid >> 6;
  const int wm = wid & 1, wn = wid >> 1;
  const int qd = lane >> 4, l15 = lane & 15;

  const int rA0 = tid >> 2, rA1 = rA0 + 64;
  const int pA0 = (tid & 3) ^ ((rA0 >> 1) & 3);
  const int pA1 = (tid & 3) ^ ((rA1 >> 1) & 3);
  int mA0 = mt * 128 + rA0; if (mA0 >= cnt) mA0 = cnt - 1;
  int mA1 = mt * 128 + rA1; if (mA1 >= cnt) mA1 = cnt - 1;
  const int tok0 = perm[e * TOK + mA0];
  const int tok1 = perm[e * TOK + mA1];
  const __bf16* gA0 = x_bf + (size_t)tok0 * DDIM + pA0 * 8;
  const __bf16* gA1 = x_bf + (size_t)tok1 * DDIM + pA1 * 8;
  const __bf16* Wte = W1t + (size_t)e * HDIM * DDIM;
  const __bf16* gB0 = Wte + (size_t)(nt * 128 + rA0) * DDIM + pA0 * 8;
  const __bf16* gB1 = Wte + (size_t)(nt * 128 + rA1) * DDIM + pA1 * 8;

#define STAGE1(buf, kk) do { \
    load16_lds(gA0 + (kk), &As[buf][tid * 8]); \
    load16_lds(gA1 + (kk), &As[buf][(tid + 256) * 8]); \
    load16_lds(gB0 + (kk), &Bs[buf][tid * 8]); \
    load16_lds(gB1 + (kk), &Bs[buf][(tid + 256) * 8]); \
  } while (0)

#define COMPUTE1(buf) do { \
    bf16x8 af[4], bfr[4]; \
    _Pragma("unroll") \
    for (int i = 0; i < 4; ++i) { \
      int r = wm * 64 + i * 16 + l15; \
      int ch = r * 4 + (qd ^ ((r >> 1) & 3)); \
      af[i] = *(const bf16x8*)(&As[buf][ch * 8]); \
    } \
    _Pragma("unroll") \
    for (int j = 0; j < 4; ++j) { \
      int r = wn * 64 + j * 16 + l15; \
      int ch = r * 4 + (qd ^ ((r >> 1) & 3)); \
      bfr[j] = *(const bf16x8*)(&Bs[buf][ch * 8]); \
    } \
    _Pragma("unroll") \
    for (int i = 0; i < 4; ++i) \
      _Pragma("unroll") \
      for (int j = 0; j < 4; ++j) \
        acc[i][j] = __builtin_amdgcn_mfma_f32_16x16x32_bf16(af[i], bfr[j], acc[i][j], 0, 0, 0); \
  } while (0)

  f32x4 acc[4][4] = {};

  STAGE1(0, 0);
  int cur = 0;
#pragma unroll 1
  for (int it = 0; it < 31; ++it) {
    STAGE1(cur ^ 1, (it + 1) * 32);
    asm volatile("s_waitcnt vmcnt(4)" ::: "memory");
    __builtin_amdgcn_sched_barrier(0);
    __builtin_amdgcn_s_barrier();
    __builtin_amdgcn_sched_barrier(0);
    COMPUTE1(cur);
    __builtin_amdgcn_sched_barrier(0);
    __builtin_amdgcn_s_barrier();
    __builtin_amdgcn_sched_barrier(0);
    cur ^= 1;
  }
  asm volatile("s_waitcnt vmcnt(0)" ::: "memory");
  __builtin_amdgcn_sched_barrier(0);
  __builtin_amdgcn_s_barrier();
  __builtin_amdgcn_sched_barrier(0);
  COMPUTE1(cur);
#undef STAGE1
#undef COMPUTE1

  const float* b1e = b1 + (size_t)e * HDIM;
#pragma unroll
  for (int i = 0; i < 4; ++i) {
#pragma unroll
    for (int v = 0; v < 4; ++v) {
      const int rl = wm * 64 + i * 16 + qd * 4 + v;
      const int m  = mt * 128 + rl;
      if (m < cnt) {
        __bf16* hrow = h_bf + (size_t)(pfx + m) * HDIM;
#pragma unroll
        for (int j = 0; j < 4; ++j) {
          const int col = nt * 128 + wn * 64 + j * 16 + l15;
          float hv = acc[i][j][v] + b1e[col];
          hv = fmaxf(hv, 0.f);
          hrow[col] = (__bf16)hv;
        }
      }
    }
  }
}

// ---------------- grouped GEMM2 (split-K=4, bf16 partials, counted-vmcnt depth-1) --------
__global__ __launch_bounds__(256, 2) void gemm2_kernel(
    const __bf16* __restrict__ h_bf, const __bf16* __restrict__ W2t,
    __bf16* __restrict__ Y,
    const int* __restrict__ counts)
{
  const int bid = blockIdx.x;
  const int ks  = bid & 3;
  const int nt  = (bid >> 2) & 7;
  const int mt  = (bid >> 5) & 31;
  const int e   = bid >> 10;
  const int cnt = counts[e];
  if (mt * 128 >= cnt) return;
  int pfx = 0;
#pragma unroll
  for (int i = 0; i < EXP; ++i) if (i < e) pfx += counts[i];

  __shared__ __align__(16) __bf16 As[2][4096];
  __shared__ __align__(16) __bf16 Bs[2][4096];

  const int tid  = threadIdx.x;
  const int lane = tid & 63, wid = tid >> 6;
  const int wm = wid & 1, wn = wid >> 1;
  const int qd = lane >> 4, l15 = lane & 15;

  const int rA0 = tid >> 2, rA1 = rA0 + 64;
  const int pA0 = (tid & 3) ^ ((rA0 >> 1) & 3);
  const int pA1 = (tid & 3) ^ ((rA1 >> 1) & 3);
  const __bf16* gA0 = h_bf + (size_t)(pfx + mt * 128 + rA0) * HDIM + pA0 * 8;
  const __bf16* gA1 = h_bf + (size_t)(pfx + mt * 128 + rA1) * HDIM + pA1 * 8;
  const __bf16* Wte = W2t + (size_t)e * DDIM * HDIM;
  const __bf16* gB0 = Wte + (size_t)(nt * 128 + rA0) * HDIM + pA0 * 8;
  const __bf16* gB1 = Wte + (size_t)(nt * 128 + rA1) * HDIM + pA1 * 8;

#define STAGE2(buf, kk) do { \
    load16_lds(gA0 + (kk), &As[buf][tid * 8]); \
    load16_lds(gA1 + (kk), &As[buf][(tid + 256) * 8]); \
    load16_lds(gB0 + (kk), &Bs[buf][tid * 8]); \
    load16_lds(gB1 + (kk), &Bs[buf][(tid + 256) * 8]); \
  } while (0)

#define COMPUTE2(buf) do { \
    bf16x8 af[4], bfr[4]; \
    _Pragma("unroll") \
    for (int i = 0; i < 4; ++i) { \
      int r = wm * 64 + i * 16 + l15; \
      int ch = r * 4 + (qd ^ ((r >> 1) & 3)); \
      af[i] = *(const bf16x8*)(&As[buf][ch * 8]); \
    } \
    _Pragma("unroll") \
    for (int j = 0; j < 4; ++j) { \
      int r = wn * 64 + j * 16 + l15; \
      int ch = r * 4 + (qd ^ ((r >> 1) & 3)); \
      bfr[j] = *(const bf16x8*)(&Bs[buf][ch * 8]); \
    } \
    _Pragma("unroll") \
    for (int i = 0; i < 4; ++i) \
      _Pragma("unroll") \
      for (int j = 0; j < 4; ++j) \
        acc[i][j] = __builtin_amdgcn_mfma_f32_16x16x32_bf16(af[i], bfr[j], acc[i][j], 0, 0, 0); \
  } while (0)

  f32x4 acc[4][4] = {};

  const int kbeg = ks * (HDIM / 4);
  STAGE2(0, kbeg);
  int cur = 0;
#pragma unroll 1
  for (int it = 0; it < 31; ++it) {
    STAGE2(cur ^ 1, kbeg + (it + 1) * 32);
    asm volatile("s_waitcnt vmcnt(4)" ::: "memory");
    __builtin_amdgcn_sched_barrier(0);
    __builtin_amdgcn_s_barrier();
    __builtin_amdgcn_sched_barrier(0);
    COMPUTE2(cur);
    __builtin_amdgcn_sched_barrier(0);
    __builtin_amdgcn_s_barrier();
    __builtin_amdgcn_sched_barrier(0);
    cur ^= 1;
  }
  asm volatile("s_waitcnt vmcnt(0)" ::: "memory");
  __builtin_amdgcn_sched_barrier(0);
  __builtin_amdgcn_s_barrier();
  __builtin_amdgcn_sched_barrier(0);
  COMPUTE2(cur);
#undef STAGE2
#undef COMPUTE2

  __bf16* Ys = Y + (size_t)ks * (2 * TOK) * DDIM;
#pragma unroll
  for (int i = 0; i < 4; ++i) {
#pragma unroll
    for (int v = 0; v < 4; ++v) {
      const int rl = wm * 64 + i * 16 + qd * 4 + v;
      const int m  = mt * 128 + rl;
      if (m < cnt) {
        __bf16* yrow = Ys + (size_t)(pfx + m) * DDIM;
#pragma unroll
        for (int j = 0; j < 4; ++j) {
          const int col = nt * 128 + wn * 64 + j * 16 + l15;
          yrow[col] = (__bf16)acc[i][j][v];
        }
      }
    }
  }
}

// ---------------- combine: out[t] = sum_j w_j * (sum_s Y[s][g_j] + b2[e_j]) ----------------
__global__ __launch_bounds__(256) void combine_kernel(
    const __bf16* __restrict__ Y, const float* __restrict__ b2,
    const float* __restrict__ wgt, const int4* __restrict__ tok2exp,
    const int* __restrict__ counts, float* __restrict__ out)
{
  const int t = blockIdx.x;
  const int c = threadIdx.x * 4;
  const int4 m = tok2exp[t];
  int base0 = 0, base1 = 0;
#pragma unroll
  for (int i = 0; i < EXP; ++i) {
    int cc = counts[i];
    if (i < m.x) base0 += cc;
    if (i < m.z) base1 += cc;
  }
  const int g0 = base0 + m.y;
  const int g1 = base1 + m.w;
  const float w0 = wgt[m.x * TOK + m.y];
  const float w1 = wgt[m.z * TOK + m.w];
  const size_t slab = (size_t)(2 * TOK) * DDIM;

  float s0x = 0.f, s0y = 0.f, s0z = 0.f, s0w = 0.f;
  float s1x = 0.f, s1y = 0.f, s1z = 0.f, s1w = 0.f;
#pragma unroll
  for (int s = 0; s < 4; ++s) {
    bf16x4 a = *(const bf16x4*)(Y + s * slab + (size_t)g0 * DDIM + c);
    bf16x4 b = *(const bf16x4*)(Y + s * slab + (size_t)g1 * DDIM + c);
    s0x += (float)a[0]; s0y += (float)a[1]; s0z += (float)a[2]; s0w += (float)a[3];
    s1x += (float)b[0]; s1y += (float)b[1]; s1z += (float)b[2]; s1w += (float)b[3];
  }
  float4 be0 = *(const float4*)(b2 + (size_t)m.x * DDIM + c);
  float4 be1 = *(const float4*)(b2 + (size_t)m.z * DDIM + c);
  float4 r;
  r.x = w0 * (s0x + be0.x) + w1 * (s1x + be1.x);
  r.y = w0 * (s0y + be0.y) + w1 * (s1y + be1.y);
  r.z = w0 * (s0z + be0.z) + w1 * (s1z + be1.z);
  r.w = w0 * (s0w + be0.w) + w1 * (s1w + be1.w);
  *(float4*)(out + (size_t)t * DDIM + c) = r;
}

extern "C" void kernel_launch(void* const* d_in, const int* in_sizes, int n_in,
                              void* d_out, int out_size, void* d_ws, size_t ws_size,
                              hipStream_t stream)
{
  const float* x  = (const float*)d_in[0];
  const float* Wg = (const float*)d_in[1];
  const float* W1 = (const float*)d_in[2];
  const float* b1 = (const float*)d_in[3];
  const float* W2 = (const float*)d_in[4];
  const float* b2 = (const float*)d_in[5];
  float* out = (float*)d_out;

  char* ws = (char*)d_ws;
  int*    counts  = (int*)(ws + OFF_COUNTS);
  int*    perm    = (int*)(ws + OFF_PERM);
  float*  wgt     = (float*)(ws + OFF_WGT);
  __bf16* x_bf    = (__bf16*)(ws + OFF_XBF);
  __bf16* W1t     = (__bf16*)(ws + OFF_W1T);
  __bf16* W2t     = (__bf16*)(ws + OFF_W2T);
  __bf16* h_bf    = (__bf16*)(ws + OFF_HBF);
  int4*   tok2exp = (int4*)(ws + OFF_T2E);
  __bf16* Y       = (__bf16*)(ws + OFF_W1T);   // aliases W1t (dead after gemm1)

  hipMemsetAsync(counts, 0, 256, stream);

  // 64 gate blocks FIRST (so they overlap the transpose stream), then 16384 transpose blocks
  prep_kernel<<<64 + 16384, 256, 0, stream>>>(W1, W2, W1t, W2t,
                                              x, Wg, x_bf, counts, perm, wgt, tok2exp);
  gemm1_kernel<<<EXP * 32 * 32, 256, 0, stream>>>(x_bf, W1t, b1, h_bf, perm, counts);
  gemm2_kernel<<<EXP * 32 * 8 * 4, 256, 0, stream>>>(h_bf, W2t, Y, counts);
  combine_kernel<<<TOK, 256, 0, stream>>>(Y, b2, wgt, tok2exp, counts, out);
}